// Round 4
// baseline (156.276 us; speedup 1.0000x reference)
//
#include <hip/hip_runtime.h>
#include <math.h>

#define VOX_N    256
#define NLINKS   8
#define NSPH     8

// Opaque single-rounded f32 ops (inline asm, NON-volatile): pins the exact
// instruction/rounding but lets the scheduler reorder by data deps only —
// volatile would force program-order between ALL asm statements, which
// serialized the 8 gathers behind each iteration's pen/max chain in R8.
__device__ __forceinline__ float fmul_o(float a, float b) {
    float r;
    asm("v_mul_f32 %0, %1, %2" : "=v"(r) : "v"(a), "v"(b));
    return r;
}
__device__ __forceinline__ float fadd_o(float a, float b) {
    float r;
    asm("v_add_f32 %0, %1, %2" : "=v"(r) : "v"(a), "v"(b));
    return r;
}

// R4 DECOMPOSITION EXPERIMENT: exact R0 baseline kernel (127.5µs, absmax 0),
// launched TWICE. The kernel is idempotent, so output is identical; the
// dur_us delta vs R0 directly measures the warm in-timed-window kernel cost
// W. Purpose: discriminate "harness floor + ~43µs kernel" vs "kernel is
// genuinely ~127µs when timed" — R1 (prefetch, +6.7µs) and R3 (NT, +7.6µs)
// jointly falsified both cache-state theories and fit either remaining one.
//
// NUMERICS CONTRACT (hard-won across R0-R8; verified absmax == 0.0):
//  - pts: plain f32 mul/add chain, DESCENDING j:
//      q = ((r2*c2 + r1*c1) + r0*c0) + p,  every op rounds once (no FMA).
//  - voxel: floor((q + 1.28f) * 100.0f) — RECIPROCAL-MULTIPLY, not divide
//    (f32(1/0.01f) == exactly 100.0f; true divide FAILS at absmax 0.1875).
//    f64 anywhere fails worse (0.4375). Comparison is bf16-quantized, only
//    voxel flips are visible — these two choices are the whole ballgame.
//  - tail: max (exact-assoc, any order), +(-0.01f), clip[0,0.5], *4
//    (exact), butterfly l-sum (== numpy n=8 pairwise tree), * weight.
__global__ __launch_bounds__(256) void voxel_cost_kernel(
    const float* __restrict__ pos,   // [B*H*L*3]
    const float* __restrict__ rot,   // [B*H*L*9]
    const float* __restrict__ cen,   // [L*S*3]
    const float* __restrict__ rad,   // [L*S]
    const float* __restrict__ sdf,   // [256^3]
    const float* __restrict__ wgt,   // [1]
    float* __restrict__ out,         // [B*H]
    int total)                       // B*H*L
{
    __shared__ float s_cen[NLINKS * NSPH * 3];
    __shared__ float s_rad[NLINKS * NSPH];

    const int t = threadIdx.x;
    if (t < NLINKS * NSPH * 3) s_cen[t] = cen[t];
    if (t < NLINKS * NSPH)     s_rad[t] = rad[t];
    __syncthreads();

    const int gid = blockIdx.x * 256 + t;
    if (gid >= total) return;
    const int l = gid & (NLINKS - 1);

    // per-thread rotation (row-major 3x3) and translation
    const size_t rbase = (size_t)gid * 9;
    const float r0 = rot[rbase + 0], r1 = rot[rbase + 1], r2 = rot[rbase + 2];
    const float r3 = rot[rbase + 3], r4 = rot[rbase + 4], r5 = rot[rbase + 5];
    const float r6 = rot[rbase + 6], r7 = rot[rbase + 7], r8 = rot[rbase + 8];
    const size_t pbase = (size_t)gid * 3;
    const float p0 = pos[pbase + 0], p1 = pos[pbase + 1], p2 = pos[pbase + 2];

    // Phase 1: compute all 24 voxel indices, issue all 8 independent
    // gathers (memory-level parallelism: one latency, not eight).
    float g[NSPH];
    #pragma unroll
    for (int s = 0; s < NSPH; ++s) {
        const int cs = (l * NSPH + s) * 3;
        const float c0 = s_cen[cs + 0];
        const float c1 = s_cen[cs + 1];
        const float c2 = s_cen[cs + 2];
        // DESCENDING-j plain chain: ((r2*c2 + r1*c1) + r0*c0) + p
        const float q0 = fadd_o(fadd_o(fadd_o(fmul_o(r2, c2), fmul_o(r1, c1)), fmul_o(r0, c0)), p0);
        const float q1 = fadd_o(fadd_o(fadd_o(fmul_o(r5, c2), fmul_o(r4, c1)), fmul_o(r3, c0)), p1);
        const float q2 = fadd_o(fadd_o(fadd_o(fmul_o(r8, c2), fmul_o(r7, c1)), fmul_o(r6, c0)), p2);
        // voxel index: floor((q + 1.28f) * 100.0f), clip to [0,255]
        const int ix = min(max((int)floorf(fmul_o(fadd_o(q0, 1.28f), 100.0f)), 0), VOX_N - 1);
        const int iy = min(max((int)floorf(fmul_o(fadd_o(q1, 1.28f), 100.0f)), 0), VOX_N - 1);
        const int iz = min(max((int)floorf(fmul_o(fadd_o(q2, 1.28f), 100.0f)), 0), VOX_N - 1);
        g[s] = sdf[(((ix << 8) + iy) << 8) + iz];
    }

    // Phase 2: combine. pen = rad - g; max over spheres (exact-assoc).
    float m = -3.402823466e38f;
    #pragma unroll
    for (int s = 0; s < NSPH; ++s) {
        const float pen = fadd_o(s_rad[l * NSPH + s], -g[s]);
        m = fmaxf(m, pen);
    }

    // res + DIST_THRESHOLD, clip to [0, 0.5], / 0.25 (exact *4)
    float res = fadd_o(m, -0.01f);
    res = fminf(fmaxf(res, 0.0f), 0.5f) * 4.0f;

    // sum over l: 8 consecutive lanes share (b,h); butterfly tree equals
    // numpy n=8 pairwise sum ((a0+a1)+(a2+a3))+((a4+a5)+(a6+a7))
    res = fadd_o(res, __shfl_xor(res, 1, 64));
    res = fadd_o(res, __shfl_xor(res, 2, 64));
    res = fadd_o(res, __shfl_xor(res, 4, 64));

    if (l == 0) out[gid >> 3] = fmul_o(wgt[0], res);
}

extern "C" void kernel_launch(void* const* d_in, const int* in_sizes, int n_in,
                              void* d_out, int out_size, void* d_ws, size_t ws_size,
                              hipStream_t stream) {
    const float* pos = (const float*)d_in[0];  // link_pos_seq [B,H,L,3]
    const float* rot = (const float*)d_in[1];  // link_rot_seq [B,H,L,3,3]
    const float* cen = (const float*)d_in[2];  // sphere_centers [L,S,3]
    const float* rad = (const float*)d_in[3];  // sphere_radii [L,S]
    const float* sdf = (const float*)d_in[4];  // sdf_grid [256,256,256]
    const float* wgt = (const float*)d_in[5];  // weight scalar
    float* out = (float*)d_out;                // [B,H]

    const int total = in_sizes[0] / 3;         // B*H*L = 262144
    const int blocks = (total + 255) / 256;

    // Launch 1: the real (cold) pass.
    hipLaunchKernelGGL(voxel_cost_kernel, dim3(blocks), dim3(256), 0, stream,
                       pos, rot, cen, rad, sdf, wgt, out, total);
    // Launch 2: identical, idempotent — its marginal cost IS the warm
    // in-timed-window kernel time W (decomposition measurement).
    hipLaunchKernelGGL(voxel_cost_kernel, dim3(blocks), dim3(256), 0, stream,
                       pos, rot, cen, rad, sdf, wgt, out, total);
}

// Round 5
// 126.665 us; speedup vs baseline: 1.2338x; 1.2338x over previous
//
#include <hip/hip_runtime.h>
#include <math.h>

#define VOX_N    256
#define NLINKS   8
#define NSPH     8

// Opaque single-rounded f32 ops (inline asm, NON-volatile): pins the exact
// instruction/rounding but lets the scheduler reorder by data deps only —
// volatile would force program-order between ALL asm statements, which
// serialized the 8 gathers behind each iteration's pen/max chain in R8.
__device__ __forceinline__ float fmul_o(float a, float b) {
    float r;
    asm("v_mul_f32 %0, %1, %2" : "=v"(r) : "v"(a), "v"(b));
    return r;
}
__device__ __forceinline__ float fadd_o(float a, float b) {
    float r;
    asm("v_add_f32 %0, %1, %2" : "=v"(r) : "v"(a), "v"(b));
    return r;
}

// FINAL KERNEL — restored R0 baseline (best measured: 127.5µs, absmax 0.0).
//
// SESSION BUDGET MODEL (established by R1/R3/R4 experiments):
//   dur_us ≈ 90µs harness floor (poison fills inside the timed window;
//            256MiB WRITE_SIZE each at ~6.6 TB/s — not kernel-addressable)
//          + ~37µs cold kernel (warm = 28.8µs, measured by R4 double-launch).
//   Warm kernel = 2M random gathers / 29µs ≈ 69G lines/s ≈ 4.4 TB/s of
//   64B-line traffic — at the Infinity-Cache random-access ceiling.
//   R1 measured that pre-warming costs (11µs) more than the cold-warm gap
//   (8µs); R3 measured that NT/no-allocate loads lose the L2/L3 reuse
//   (+8µs). Both directions are net-negative → this structure is optimal.
//
// NUMERICS CONTRACT (hard-won across R0-R8; verified absmax == 0.0):
//  - pts: plain f32 mul/add chain, DESCENDING j:
//      q = ((r2*c2 + r1*c1) + r0*c0) + p,  every op rounds once (no FMA).
//  - voxel: floor((q + 1.28f) * 100.0f) — RECIPROCAL-MULTIPLY, not divide
//    (f32(1/0.01f) == exactly 100.0f; true divide FAILS at absmax 0.1875).
//    f64 anywhere fails worse (0.4375). Comparison is bf16-quantized, only
//    voxel flips are visible — these two choices are the whole ballgame.
//  - tail: max (exact-assoc, any order), +(-0.01f), clip[0,0.5], *4
//    (exact), butterfly l-sum (== numpy n=8 pairwise tree), * weight.
__global__ __launch_bounds__(256) void voxel_cost_kernel(
    const float* __restrict__ pos,   // [B*H*L*3]
    const float* __restrict__ rot,   // [B*H*L*9]
    const float* __restrict__ cen,   // [L*S*3]
    const float* __restrict__ rad,   // [L*S]
    const float* __restrict__ sdf,   // [256^3]
    const float* __restrict__ wgt,   // [1]
    float* __restrict__ out,         // [B*H]
    int total)                       // B*H*L
{
    __shared__ float s_cen[NLINKS * NSPH * 3];
    __shared__ float s_rad[NLINKS * NSPH];

    const int t = threadIdx.x;
    if (t < NLINKS * NSPH * 3) s_cen[t] = cen[t];
    if (t < NLINKS * NSPH)     s_rad[t] = rad[t];
    __syncthreads();

    const int gid = blockIdx.x * 256 + t;
    if (gid >= total) return;
    const int l = gid & (NLINKS - 1);

    // per-thread rotation (row-major 3x3) and translation
    const size_t rbase = (size_t)gid * 9;
    const float r0 = rot[rbase + 0], r1 = rot[rbase + 1], r2 = rot[rbase + 2];
    const float r3 = rot[rbase + 3], r4 = rot[rbase + 4], r5 = rot[rbase + 5];
    const float r6 = rot[rbase + 6], r7 = rot[rbase + 7], r8 = rot[rbase + 8];
    const size_t pbase = (size_t)gid * 3;
    const float p0 = pos[pbase + 0], p1 = pos[pbase + 1], p2 = pos[pbase + 2];

    // Phase 1: compute all 24 voxel indices, issue all 8 independent
    // gathers (memory-level parallelism: one latency, not eight).
    float g[NSPH];
    #pragma unroll
    for (int s = 0; s < NSPH; ++s) {
        const int cs = (l * NSPH + s) * 3;
        const float c0 = s_cen[cs + 0];
        const float c1 = s_cen[cs + 1];
        const float c2 = s_cen[cs + 2];
        // DESCENDING-j plain chain: ((r2*c2 + r1*c1) + r0*c0) + p
        const float q0 = fadd_o(fadd_o(fadd_o(fmul_o(r2, c2), fmul_o(r1, c1)), fmul_o(r0, c0)), p0);
        const float q1 = fadd_o(fadd_o(fadd_o(fmul_o(r5, c2), fmul_o(r4, c1)), fmul_o(r3, c0)), p1);
        const float q2 = fadd_o(fadd_o(fadd_o(fmul_o(r8, c2), fmul_o(r7, c1)), fmul_o(r6, c0)), p2);
        // voxel index: floor((q + 1.28f) * 100.0f), clip to [0,255]
        const int ix = min(max((int)floorf(fmul_o(fadd_o(q0, 1.28f), 100.0f)), 0), VOX_N - 1);
        const int iy = min(max((int)floorf(fmul_o(fadd_o(q1, 1.28f), 100.0f)), 0), VOX_N - 1);
        const int iz = min(max((int)floorf(fmul_o(fadd_o(q2, 1.28f), 100.0f)), 0), VOX_N - 1);
        g[s] = sdf[(((ix << 8) + iy) << 8) + iz];
    }

    // Phase 2: combine. pen = rad - g; max over spheres (exact-assoc).
    float m = -3.402823466e38f;
    #pragma unroll
    for (int s = 0; s < NSPH; ++s) {
        const float pen = fadd_o(s_rad[l * NSPH + s], -g[s]);
        m = fmaxf(m, pen);
    }

    // res + DIST_THRESHOLD, clip to [0, 0.5], / 0.25 (exact *4)
    float res = fadd_o(m, -0.01f);
    res = fminf(fmaxf(res, 0.0f), 0.5f) * 4.0f;

    // sum over l: 8 consecutive lanes share (b,h); butterfly tree equals
    // numpy n=8 pairwise sum ((a0+a1)+(a2+a3))+((a4+a5)+(a6+a7))
    res = fadd_o(res, __shfl_xor(res, 1, 64));
    res = fadd_o(res, __shfl_xor(res, 2, 64));
    res = fadd_o(res, __shfl_xor(res, 4, 64));

    if (l == 0) out[gid >> 3] = fmul_o(wgt[0], res);
}

extern "C" void kernel_launch(void* const* d_in, const int* in_sizes, int n_in,
                              void* d_out, int out_size, void* d_ws, size_t ws_size,
                              hipStream_t stream) {
    const float* pos = (const float*)d_in[0];  // link_pos_seq [B,H,L,3]
    const float* rot = (const float*)d_in[1];  // link_rot_seq [B,H,L,3,3]
    const float* cen = (const float*)d_in[2];  // sphere_centers [L,S,3]
    const float* rad = (const float*)d_in[3];  // sphere_radii [L,S]
    const float* sdf = (const float*)d_in[4];  // sdf_grid [256,256,256]
    const float* wgt = (const float*)d_in[5];  // weight scalar
    float* out = (float*)d_out;                // [B,H]

    const int total = in_sizes[0] / 3;         // B*H*L = 262144
    const int blocks = (total + 255) / 256;
    hipLaunchKernelGGL(voxel_cost_kernel, dim3(blocks), dim3(256), 0, stream,
                       pos, rot, cen, rad, sdf, wgt, out, total);
}